// Round 21
// baseline (134.258 us; speedup 1.0000x reference)
//
#include <hip/hip_runtime.h>
#include <math.h>

// EdgeConditionedConv on MI355X — round 20: 128-edge blocks, nt=8.
// r10 showed halving MFMA:A-load ratio hurts; this doubles it (32 MFMA per
// 4 Wpk loads/j) and halves Wpk L2 restreaming (782->391 MB). hf[8][4]
// resident (unified reg budget at 2 waves/SIMD); P reused across two
// nt-halves per j. mlp1 broadcast-W1 (r19-proven), 2 edges/lane.
// msgred pitch 131 (odd -> 2-way scatter reads). gru/prep r19-identical.

constexpr int N_NODES  = 25000;
constexpr int N_EDGES  = 50000;
constexpr int NODE_DIM = 64;
constexpr int EDGE_DIM = 16;
constexpr int HID      = 128;
constexpr int FS       = 65;           // hshf fragment stride (half8 units)
constexpr int BE       = 128;          // edges per edge_msg block
constexpr int MP       = 131;          // msgred pitch (floats)

typedef __attribute__((ext_vector_type(8))) _Float16 half8;
typedef __attribute__((ext_vector_type(4))) float    f32x4;

constexpr int G_MS  = 128;             // agg-zero blocks
constexpr int G_PK  = 270;             // prepack blocks (270*256 = 69120 items)

// ---------------------------------------------------------------- prep
__global__ __launch_bounds__(256) void prep_kernel(
    const float* __restrict__ W2, const float* __restrict__ b2,
    const float* __restrict__ w_ih, const float* __restrict__ w_hh,
    _Float16* __restrict__ Wpk, _Float16* __restrict__ b2pk,
    _Float16* __restrict__ gpk, float* __restrict__ agg)
{
    int b = blockIdx.x;
    if (b < G_MS) {
        float4* a4 = (float4*)agg;
        const float4 z = make_float4(0.f, 0.f, 0.f, 0.f);
        for (int i = b * 256 + threadIdx.x; i < N_NODES * NODE_DIM / 4; i += G_MS * 256)
            a4[i] = z;
        return;
    }
    int c = (b - G_MS) * 256 + threadIdx.x;
    if (c < 65536) {
        int lane = c & 63, mt = (c >> 6) & 3, ks = (c >> 8) & 3, j = c >> 10;
        int i   = mt * 16 + (lane & 15);
        int col = ks * 32 + ((lane >> 4) & 3) * 8;
        const float* src = W2 + (size_t)(i * 64 + j) * HID + col;
        half8 o;
#pragma unroll
        for (int q = 0; q < 8; ++q) o[q] = (_Float16)src[q];
        ((half8*)Wpk)[c] = o;
    } else if (c < 65536 + 512) {
        int c2 = c - 65536;
        int lane = c2 & 63, mt = (c2 >> 6) & 3, ks2 = (c2 >> 8) & 1;
        int i = mt * 16 + (lane & 15);
        int j = ks2 * 32 + ((lane >> 4) & 3) * 8;
        const float* src = b2 + i * 64 + j;
        half8 o;
#pragma unroll
        for (int q = 0; q < 8; ++q) o[q] = (_Float16)src[q];
        ((half8*)b2pk)[c2] = o;
    } else if (c < 65536 + 512 + 3072) {
        // GRU weight fragments: chunk c3 = ((mat*12+nt)*2+ks)*64 + lane
        int c3 = c - (65536 + 512);
        int lane = c3 & 63, ks = (c3 >> 6) & 1;
        int t2 = c3 >> 7;             // mat*12 + nt, in [0,24)
        int nt = t2 % 12, mat = t2 / 12;
        int g = nt * 16 + (lane & 15);
        int k = ks * 32 + ((lane >> 4) & 3) * 8;
        const float* src = (mat == 0 ? w_ih : w_hh) + (size_t)g * 64 + k;
        half8 o;
#pragma unroll
        for (int q = 0; q < 8; ++q) o[q] = (_Float16)src[q];
        ((half8*)gpk)[c3] = o;
    }
}

// ---------------------------------------------------------------- phase 2
// 4 waves; wave mt owns output rows [mt*16,mt*16+16) for ALL j and ALL 128
// edges (nt=0..7). Per j: 4 prefetched A-loads, 32 MFMA (two nt-halves
// sharing P[4]), f32 gv epilogue. mlp1 in-block (broadcast W1, 2 edges/lane).
__global__ __launch_bounds__(256, 2) void edge_msg_mfma_kernel(
    const float*    __restrict__ edge_attr,
    const float*    __restrict__ W1,
    const float*    __restrict__ b1,
    const float*    __restrict__ x,
    const int*      __restrict__ edge_index,   // [2][E] int32
    const _Float16* __restrict__ Wpk,
    const _Float16* __restrict__ b2pk,
    float* __restrict__ agg)                   // [N][64], pre-zeroed
{
    __shared__ float xsh[BE * 68];      // gathered x[src], pitch 68 (34816 B)
    __shared__ float msgred[64 * MP];   // [i][e], pitch 131 (33536 B)
    __shared__ float W1s[128 * 16];     // 8192 B
    __shared__ float b1s[128];
    __shared__ int   dsts[BE];
    half8* hshf = (half8*)msgred;       // alias: 32 fragments x FS=65 half8 (33280 B)

    const int e0   = blockIdx.x * BE;
    const int t    = threadIdx.x;
    const int mt   = t >> 6;            // wave id
    const int lane = t & 63;

    // ---- gather x[src[e]] rows into xsh (zero-fill invalid) + dsts
    if (t < BE) dsts[t] = (e0 + t < N_EDGES) ? edge_index[N_EDGES + e0 + t] : -1;
#pragma unroll
    for (int r = 0; r < 8; ++r) {
        int idx = t + r * 256;            // 0..2047 float4 slots
        int le = idx >> 4, q = idx & 15;
        int e = e0 + le;
        float4 v = make_float4(0.f, 0.f, 0.f, 0.f);
        if (e < N_EDGES) {
            int s = edge_index[e];
            if ((unsigned)s < (unsigned)N_NODES)
                v = ((const float4*)x)[(size_t)s * 16 + q];
        }
        *(float4*)&xsh[le * 68 + q * 4] = v;
    }

    // ---- stage W1/b1
#pragma unroll
    for (int r = 0; r < 8; ++r) W1s[t + r * 256] = W1[t + r * 256];
    if (t < 128) b1s[t] = b1[t];
    __syncthreads();

    // ---- in-block mlp1, wave-uniform k (broadcast W1s/b1s reads).
    // Wave ks=mt computes k in [ks*32,ks*32+32) for all 128 edges
    // (2 edges per lane: el = p*64 + lane).
    {
        const int ks = mt;
#pragma unroll
        for (int p = 0; p < 2; ++p) {
            int el = p * 64 + lane;
            int e = e0 + el;
            float ea[16];
            if (e < N_EDGES) {
                const float4* ea4 = (const float4*)(edge_attr + (size_t)e * EDGE_DIM);
#pragma unroll
                for (int q = 0; q < 4; ++q) {
                    float4 v = ea4[q];
                    ea[q * 4] = v.x; ea[q * 4 + 1] = v.y; ea[q * 4 + 2] = v.z; ea[q * 4 + 3] = v.w;
                }
            } else {
#pragma unroll
                for (int d = 0; d < 16; ++d) ea[d] = 0.f;
            }
            const int fbase = ((el >> 4) * 4 + ks) * FS + (el & 15);
#pragma unroll
            for (int kc = 0; kc < 4; ++kc) {      // 4 chunks of 8 k-values
                half8 hh;
#pragma unroll
                for (int kk = 0; kk < 8; ++kk) {
                    int k = ks * 32 + kc * 8 + kk;      // wave-uniform
                    float acc = b1s[k];
                    const float* w = &W1s[k * 16];      // broadcast reads
#pragma unroll
                    for (int d = 0; d < EDGE_DIM; ++d) acc += ea[d] * w[d];
                    float g = 0.5f * acc * (1.0f + erff(acc * 0.70710678118654752f));
                    hh[kk] = (_Float16)g;
                }
                hshf[fbase + kc * 16] = hh;
            }
        }
    }
    __syncthreads();

    // ---- resident h fragments for all 8 edge tiles (lane-contiguous reads)
    half8 hf[8][4];   // [nt][ks]
#pragma unroll
    for (int nt = 0; nt < 8; ++nt)
#pragma unroll
        for (int ks = 0; ks < 4; ++ks)
            hf[nt][ks] = hshf[(nt * 4 + ks) * FS + lane];
    __syncthreads();   // hshf dead after this point (msgred may overwrite)

    const f32x4 zero4 = {0.f, 0.f, 0.f, 0.f};
    f32x4 msg[8];
#pragma unroll
    for (int nt = 0; nt < 8; ++nt) msg[nt] = zero4;

    const half8* wpk8 = (const half8*)Wpk;
    const int mbase = mt * 64 + lane;

    half8 aA[4], aB[4];
#pragma unroll
    for (int ks = 0; ks < 4; ++ks) aA[ks] = wpk8[(size_t)mbase + ks * 256];  // j=0

#pragma unroll 1
    for (int j = 0; j < 64; j += 2) {
        {   // prefetch j+1
            size_t nb = (size_t)(j + 1) * 1024 + mbase;
#pragma unroll
            for (int ks = 0; ks < 4; ++ks) aB[ks] = wpk8[nb + ks * 256];
        }
        {   // compute j
            float gv[8];
#pragma unroll
            for (int nt = 0; nt < 8; ++nt) gv[nt] = xsh[(nt * 16 + (lane & 15)) * 68 + j];
            f32x4 P[4];
#pragma unroll
            for (int ks = 0; ks < 4; ++ks)
#pragma unroll
                for (int nt = 0; nt < 4; ++nt)
                    P[nt] = __builtin_amdgcn_mfma_f32_16x16x32_f16(
                        aA[ks], hf[nt][ks], ks == 0 ? zero4 : P[nt], 0, 0, 0);
#pragma unroll
            for (int nt = 0; nt < 4; ++nt)
#pragma unroll
                for (int r = 0; r < 4; ++r) msg[nt][r] += gv[nt] * P[nt][r];
#pragma unroll
            for (int ks = 0; ks < 4; ++ks)
#pragma unroll
                for (int nt = 4; nt < 8; ++nt)
                    P[nt - 4] = __builtin_amdgcn_mfma_f32_16x16x32_f16(
                        aA[ks], hf[nt][ks], ks == 0 ? zero4 : P[nt - 4], 0, 0, 0);
#pragma unroll
            for (int nt = 4; nt < 8; ++nt)
#pragma unroll
                for (int r = 0; r < 4; ++r) msg[nt][r] += gv[nt] * P[nt - 4][r];
        }
        if (j + 2 < 64) {   // prefetch j+2
            size_t nb = (size_t)(j + 2) * 1024 + mbase;
#pragma unroll
            for (int ks = 0; ks < 4; ++ks) aA[ks] = wpk8[nb + ks * 256];
        }
        {   // compute j+1
            float gv[8];
#pragma unroll
            for (int nt = 0; nt < 8; ++nt) gv[nt] = xsh[(nt * 16 + (lane & 15)) * 68 + j + 1];
            f32x4 P[4];
#pragma unroll
            for (int ks = 0; ks < 4; ++ks)
#pragma unroll
                for (int nt = 0; nt < 4; ++nt)
                    P[nt] = __builtin_amdgcn_mfma_f32_16x16x32_f16(
                        aB[ks], hf[nt][ks], ks == 0 ? zero4 : P[nt], 0, 0, 0);
#pragma unroll
            for (int nt = 0; nt < 4; ++nt)
#pragma unroll
                for (int r = 0; r < 4; ++r) msg[nt][r] += gv[nt] * P[nt][r];
#pragma unroll
            for (int ks = 0; ks < 4; ++ks)
#pragma unroll
                for (int nt = 4; nt < 8; ++nt)
                    P[nt - 4] = __builtin_amdgcn_mfma_f32_16x16x32_f16(
                        aB[ks], hf[nt][ks], ks == 0 ? zero4 : P[nt - 4], 0, 0, 0);
#pragma unroll
            for (int nt = 4; nt < 8; ++nt)
#pragma unroll
                for (int r = 0; r < 4; ++r) msg[nt][r] += gv[nt] * P[nt - 4][r];
        }
    }

    // ---- bias: msg[i,e] += sum_j b2[i*64+j]*g[e,j]  (this wave's rows)
#pragma unroll
    for (int ks2 = 0; ks2 < 2; ++ks2) {
        half8 bf8 = ((const half8*)b2pk)[ks2 * 256 + mt * 64 + lane];
#pragma unroll
        for (int nt = 0; nt < 8; ++nt) {
            const float* gp = &xsh[(nt * 16 + (lane & 15)) * 68 + ks2 * 32 + ((lane >> 4) & 3) * 8];
            float4 lo = *(const float4*)gp;
            float4 hi = *(const float4*)(gp + 4);
            half8 g8;
            g8[0] = (_Float16)lo.x; g8[1] = (_Float16)lo.y;
            g8[2] = (_Float16)lo.z; g8[3] = (_Float16)lo.w;
            g8[4] = (_Float16)hi.x; g8[5] = (_Float16)hi.y;
            g8[6] = (_Float16)hi.z; g8[7] = (_Float16)hi.w;
            msg[nt] = __builtin_amdgcn_mfma_f32_16x16x32_f16(bf8, g8, msg[nt], 0, 0, 0);
        }
    }

    // ---- each wave writes its exclusive 16 rows of msgred
#pragma unroll
    for (int nt = 0; nt < 8; ++nt)
#pragma unroll
        for (int r = 0; r < 4; ++r) {
            int i = mt * 16 + ((lane >> 4) & 3) * 4 + r;
            int e = nt * 16 + (lane & 15);
            msgred[i * MP + e] = msg[nt][r];
        }
    __syncthreads();

    // ---- scatter, coalesced: one edge row per atomic instr (lane = dim i)
#pragma unroll 1
    for (int ee = mt; ee < BE; ee += 4) {
        int d = dsts[ee];
        if (e0 + ee < N_EDGES && (unsigned)d < (unsigned)N_NODES)
            atomicAdd(agg + (size_t)d * NODE_DIM + lane, msgred[lane * MP + ee]);
    }
}

// ---------------------------------------------------------------- phase 3
// GRUCell via MFMA (r15-proven).
__global__ __launch_bounds__(256) void gru_mfma_kernel(
    const float* __restrict__ agg,
    const float* __restrict__ x,
    const _Float16* __restrict__ gpk,
    const float* __restrict__ b_ih,
    const float* __restrict__ b_hh,
    float* __restrict__ out)
{
    const int t = threadIdx.x, wave = t >> 6, lane = t & 63;
    const int n0 = blockIdx.x * 64;

    int arow = n0 + wave * 16 + (lane & 15);
    if (arow >= N_NODES) arow = N_NODES - 1;
    const int kcol = ((lane >> 4) & 3) * 8;
    half8 aF[2], xF[2];   // [ks]
#pragma unroll
    for (int ks = 0; ks < 2; ++ks) {
        const float* ap = agg + (size_t)arow * 64 + ks * 32 + kcol;
        const float* xp = x   + (size_t)arow * 64 + ks * 32 + kcol;
        float4 a0 = *(const float4*)ap, a1 = *(const float4*)(ap + 4);
        float4 x0 = *(const float4*)xp, x1 = *(const float4*)(xp + 4);
        half8 af, xf;
        af[0] = (_Float16)a0.x; af[1] = (_Float16)a0.y; af[2] = (_Float16)a0.z; af[3] = (_Float16)a0.w;
        af[4] = (_Float16)a1.x; af[5] = (_Float16)a1.y; af[6] = (_Float16)a1.z; af[7] = (_Float16)a1.w;
        xf[0] = (_Float16)x0.x; xf[1] = (_Float16)x0.y; xf[2] = (_Float16)x0.z; xf[3] = (_Float16)x0.w;
        xf[4] = (_Float16)x1.x; xf[5] = (_Float16)x1.y; xf[6] = (_Float16)x1.z; xf[7] = (_Float16)x1.w;
        aF[ks] = af; xF[ks] = xf;
    }

    const half8* g8 = (const half8*)gpk;
    const f32x4 zero4 = {0.f, 0.f, 0.f, 0.f};
    f32x4 accI[12], accH[12];
#pragma unroll
    for (int nt = 0; nt < 12; ++nt) {
        half8 b0 = g8[((0 * 12 + nt) * 2 + 0) * 64 + lane];
        half8 b1f = g8[((0 * 12 + nt) * 2 + 1) * 64 + lane];
        f32x4 a = __builtin_amdgcn_mfma_f32_16x16x32_f16(aF[0], b0, zero4, 0, 0, 0);
        accI[nt] = __builtin_amdgcn_mfma_f32_16x16x32_f16(aF[1], b1f, a, 0, 0, 0);
        half8 c0 = g8[((1 * 12 + nt) * 2 + 0) * 64 + lane];
        half8 c1 = g8[((1 * 12 + nt) * 2 + 1) * 64 + lane];
        f32x4 h0 = __builtin_amdgcn_mfma_f32_16x16x32_f16(xF[0], c0, zero4, 0, 0, 0);
        accH[nt] = __builtin_amdgcn_mfma_f32_16x16x32_f16(xF[1], c1, h0, 0, 0, 0);
    }

    const int nodeBase = n0 + wave * 16 + ((lane >> 4) & 3) * 4;
    const int dlo = lane & 15;
#pragma unroll
    for (int q = 0; q < 4; ++q) {
        int d = q * 16 + dlo;
        float bi0 = b_ih[d], bi1 = b_ih[64 + d], bi2 = b_ih[128 + d];
        float bh0 = b_hh[d], bh1 = b_hh[64 + d], bh2 = b_hh[128 + d];
#pragma unroll
        for (int r = 0; r < 4; ++r) {
            int node = nodeBase + r;
            if (node < N_NODES) {
                float I0 = accI[q][r] + bi0, I1 = accI[q + 4][r] + bi1, I2 = accI[q + 8][r] + bi2;
                float H0 = accH[q][r] + bh0, H1 = accH[q + 4][r] + bh1, H2 = accH[q + 8][r] + bh2;
                float rg = 1.f / (1.f + expf(-(I0 + H0)));
                float z  = 1.f / (1.f + expf(-(I1 + H1)));
                float nn = tanhf(I2 + rg * H2);
                float xv = x[(size_t)node * 64 + d];
                out[(size_t)node * 64 + d] = (1.f - z) * nn + z * xv;
            }
        }
    }
}

// ---------------------------------------------------------------- launch
extern "C" void kernel_launch(void* const* d_in, const int* in_sizes, int n_in,
                              void* d_out, int out_size, void* d_ws, size_t ws_size,
                              hipStream_t stream)
{
    const float* x          = (const float*)d_in[0];
    const int*   edge_index = (const int*)  d_in[1];
    const float* edge_attr  = (const float*)d_in[2];
    const float* W1         = (const float*)d_in[3];
    const float* b1         = (const float*)d_in[4];
    const float* W2         = (const float*)d_in[5];
    const float* b2         = (const float*)d_in[6];
    const float* w_ih       = (const float*)d_in[7];
    const float* w_hh       = (const float*)d_in[8];
    const float* b_ih       = (const float*)d_in[9];
    const float* b_hh       = (const float*)d_in[10];
    float* out = (float*)d_out;

    // ws layout: identical offsets to round 5/9/15/16 (proven; 20,355,072 B).
    char* ws = (char*)d_ws;
    ws += (size_t)N_EDGES * HID * sizeof(_Float16);         // (unused hbuf slot, 12.8 MB)
    _Float16* Wpk  = (_Float16*)ws;                         // 1 MB
    ws += (size_t)65536 * 8 * sizeof(_Float16);
    _Float16* b2pk = (_Float16*)ws;                         // 8 KB
    ws += (size_t)512 * 8 * sizeof(_Float16);
    _Float16* gpk  = (_Float16*)ws;                         // 49,152 B within the two 48 KB slots
    ws += (size_t)64 * 192 * sizeof(float);                 // 48 KB
    ws += (size_t)64 * 192 * sizeof(float);                 // 48 KB
    float* agg = (float*)ws;                                // 6.4 MB (same offset)

    prep_kernel<<<dim3(G_MS + G_PK), dim3(256), 0, stream>>>(
        W2, b2, w_ih, w_hh, Wpk, b2pk, gpk, agg);

    edge_msg_mfma_kernel<<<dim3((N_EDGES + BE - 1) / BE), dim3(256), 0, stream>>>(
        edge_attr, W1, b1, x, edge_index, Wpk, b2pk, agg);

    gru_mfma_kernel<<<dim3((N_NODES + 63) / 64), dim3(256), 0, stream>>>(
        agg, x, gpk, b_ih, b_hh, out);
}

// Round 22
// 94.282 us; speedup vs baseline: 1.4240x; 1.4240x over previous
//
#include <hip/hip_runtime.h>
#include <math.h>

// EdgeConditionedConv on MI355X — round 21: REVERT to round-19 (best: 94.3us).
// r20's nt=8 variant spilled (VGPR cap + 143MB scratch writes) -> retired.
// This is the proven configuration: fused mlp1 (broadcast-W1, wave-uniform k)
// + r9 j-loop (dist-1 prefetch, 4:1 MFMA:A-load) + MFMA GRU + 3 launches.

constexpr int N_NODES  = 25000;
constexpr int N_EDGES  = 50000;
constexpr int NODE_DIM = 64;
constexpr int EDGE_DIM = 16;
constexpr int HID      = 128;
constexpr int FS       = 65;           // hshf fragment stride (half8 units)

typedef __attribute__((ext_vector_type(8))) _Float16 half8;
typedef __attribute__((ext_vector_type(4))) float    f32x4;

constexpr int G_MS  = 128;             // agg-zero blocks
constexpr int G_PK  = 270;             // prepack blocks (270*256 = 69120 items)

// ---------------------------------------------------------------- prep
__global__ __launch_bounds__(256) void prep_kernel(
    const float* __restrict__ W2, const float* __restrict__ b2,
    const float* __restrict__ w_ih, const float* __restrict__ w_hh,
    _Float16* __restrict__ Wpk, _Float16* __restrict__ b2pk,
    _Float16* __restrict__ gpk, float* __restrict__ agg)
{
    int b = blockIdx.x;
    if (b < G_MS) {
        float4* a4 = (float4*)agg;
        const float4 z = make_float4(0.f, 0.f, 0.f, 0.f);
        for (int i = b * 256 + threadIdx.x; i < N_NODES * NODE_DIM / 4; i += G_MS * 256)
            a4[i] = z;
        return;
    }
    int c = (b - G_MS) * 256 + threadIdx.x;
    if (c < 65536) {
        int lane = c & 63, mt = (c >> 6) & 3, ks = (c >> 8) & 3, j = c >> 10;
        int i   = mt * 16 + (lane & 15);
        int col = ks * 32 + ((lane >> 4) & 3) * 8;
        const float* src = W2 + (size_t)(i * 64 + j) * HID + col;
        half8 o;
#pragma unroll
        for (int q = 0; q < 8; ++q) o[q] = (_Float16)src[q];
        ((half8*)Wpk)[c] = o;
    } else if (c < 65536 + 512) {
        int c2 = c - 65536;
        int lane = c2 & 63, mt = (c2 >> 6) & 3, ks2 = (c2 >> 8) & 1;
        int i = mt * 16 + (lane & 15);
        int j = ks2 * 32 + ((lane >> 4) & 3) * 8;
        const float* src = b2 + i * 64 + j;
        half8 o;
#pragma unroll
        for (int q = 0; q < 8; ++q) o[q] = (_Float16)src[q];
        ((half8*)b2pk)[c2] = o;
    } else if (c < 65536 + 512 + 3072) {
        // GRU weight fragments: chunk c3 = ((mat*12+nt)*2+ks)*64 + lane
        int c3 = c - (65536 + 512);
        int lane = c3 & 63, ks = (c3 >> 6) & 1;
        int t2 = c3 >> 7;             // mat*12 + nt, in [0,24)
        int nt = t2 % 12, mat = t2 / 12;
        int g = nt * 16 + (lane & 15);
        int k = ks * 32 + ((lane >> 4) & 3) * 8;
        const float* src = (mat == 0 ? w_ih : w_hh) + (size_t)g * 64 + k;
        half8 o;
#pragma unroll
        for (int q = 0; q < 8; ++q) o[q] = (_Float16)src[q];
        ((half8*)gpk)[c3] = o;
    }
}

// ---------------------------------------------------------------- phase 2
// r9-proven j-loop + in-block mlp1 (lane=edge, wave=k-range, broadcast W1).
__global__ __launch_bounds__(256, 3) void edge_msg_mfma_kernel(
    const float*    __restrict__ edge_attr,
    const float*    __restrict__ W1,
    const float*    __restrict__ b1,
    const float*    __restrict__ x,
    const int*      __restrict__ edge_index,   // [2][E] int32
    const _Float16* __restrict__ Wpk,
    const _Float16* __restrict__ b2pk,
    float* __restrict__ agg)                   // [N][64], pre-zeroed
{
    __shared__ float xsh[64 * 68];      // gathered x[src], pitch 68 (17408 B)
    __shared__ float msgred[64 * 67];   // [i][e], pitch 67 (17152 B)
    __shared__ float W1s[128 * 16];     // 8192 B
    __shared__ float b1s[128];
    __shared__ int   dsts[64];
    half8* hshf = (half8*)msgred;       // alias: 16 fragments x FS=65 half8 (16640 B)

    const int e0   = blockIdx.x * 64;
    const int t    = threadIdx.x;
    const int mt   = t >> 6;            // wave id
    const int lane = t & 63;

    // ---- gather x[src[e]] rows into xsh (zero-fill invalid) + dsts
    {
        int le = t >> 2, sub = t & 3;
        int e = e0 + le;
        int s = -1;
        if (e < N_EDGES) {
            if (sub == 0) dsts[le] = edge_index[N_EDGES + e];
            s = edge_index[e];
        } else if (sub == 0) {
            dsts[le] = -1;
        }
#pragma unroll
        for (int q = 0; q < 4; ++q) {
            float4 v = make_float4(0.f, 0.f, 0.f, 0.f);
            if ((unsigned)s < (unsigned)N_NODES)
                v = ((const float4*)x)[(size_t)s * 16 + sub * 4 + q];
            *(float4*)&xsh[le * 68 + sub * 16 + q * 4] = v;
        }
    }

    // ---- stage W1/b1
#pragma unroll
    for (int r = 0; r < 8; ++r) W1s[t + r * 256] = W1[t + r * 256];
    if (t < 128) b1s[t] = b1[t];
    __syncthreads();

    // ---- in-block mlp1, wave-uniform k: wave ks computes k in
    // [ks*32, ks*32+32) for ALL 64 edges (lane = edge). W1s/b1s reads are
    // same-address broadcasts (conflict-free).
    // h[lane][k] -> hshf[((lane>>4)*4 + ks)*FS + kc*16 + (lane&15)].
    {
        const int ks = mt;              // this wave's k-range
        int e = e0 + lane;
        float ea[16];
        if (e < N_EDGES) {
            const float4* ea4 = (const float4*)(edge_attr + (size_t)e * EDGE_DIM);
#pragma unroll
            for (int q = 0; q < 4; ++q) {
                float4 v = ea4[q];
                ea[q * 4] = v.x; ea[q * 4 + 1] = v.y; ea[q * 4 + 2] = v.z; ea[q * 4 + 3] = v.w;
            }
        } else {
#pragma unroll
            for (int d = 0; d < 16; ++d) ea[d] = 0.f;
        }
        const int fbase = ((lane >> 4) * 4 + ks) * FS + (lane & 15);
#pragma unroll
        for (int kc = 0; kc < 4; ++kc) {      // 4 chunks of 8 k-values
            half8 hh;
#pragma unroll
            for (int kk = 0; kk < 8; ++kk) {
                int k = ks * 32 + kc * 8 + kk;      // wave-uniform
                float acc = b1s[k];
                const float* w = &W1s[k * 16];      // broadcast reads
#pragma unroll
                for (int d = 0; d < EDGE_DIM; ++d) acc += ea[d] * w[d];
                float g = 0.5f * acc * (1.0f + erff(acc * 0.70710678118654752f));
                hh[kk] = (_Float16)g;
            }
            hshf[fbase + kc * 16] = hh;
        }
    }
    __syncthreads();

    // ---- per-wave resident h fragments: lane-contiguous, conflict-free
    half8 hf[4][4];   // [nt][ks]
#pragma unroll
    for (int nt = 0; nt < 4; ++nt)
#pragma unroll
        for (int ks = 0; ks < 4; ++ks)
            hf[nt][ks] = hshf[(nt * 4 + ks) * FS + lane];
    __syncthreads();   // hshf dead after this point (msgred may overwrite)

    const f32x4 zero4 = {0.f, 0.f, 0.f, 0.f};
    f32x4 msg[4];
#pragma unroll
    for (int nt = 0; nt < 4; ++nt) msg[nt] = zero4;

    const half8* wpk8 = (const half8*)Wpk;
    const int mbase = mt * 64 + lane;

    half8 aA[4], aB[4];
#pragma unroll
    for (int ks = 0; ks < 4; ++ks) aA[ks] = wpk8[(size_t)mbase + ks * 256];  // j=0

#pragma unroll 1
    for (int j = 0; j < 64; j += 2) {
        {   // prefetch j+1
            size_t nb = (size_t)(j + 1) * 1024 + mbase;
#pragma unroll
            for (int ks = 0; ks < 4; ++ks) aB[ks] = wpk8[nb + ks * 256];
        }
        {   // compute j
            float gv[4];
#pragma unroll
            for (int nt = 0; nt < 4; ++nt) gv[nt] = xsh[(nt * 16 + (lane & 15)) * 68 + j];
            f32x4 P[4];
#pragma unroll
            for (int ks = 0; ks < 4; ++ks)
#pragma unroll
                for (int nt = 0; nt < 4; ++nt)
                    P[nt] = __builtin_amdgcn_mfma_f32_16x16x32_f16(
                        aA[ks], hf[nt][ks], ks == 0 ? zero4 : P[nt], 0, 0, 0);
#pragma unroll
            for (int nt = 0; nt < 4; ++nt)
#pragma unroll
                for (int r = 0; r < 4; ++r) msg[nt][r] += gv[nt] * P[nt][r];
        }
        if (j + 2 < 64) {   // prefetch j+2
            size_t nb = (size_t)(j + 2) * 1024 + mbase;
#pragma unroll
            for (int ks = 0; ks < 4; ++ks) aA[ks] = wpk8[nb + ks * 256];
        }
        {   // compute j+1
            float gv[4];
#pragma unroll
            for (int nt = 0; nt < 4; ++nt) gv[nt] = xsh[(nt * 16 + (lane & 15)) * 68 + j + 1];
            f32x4 P[4];
#pragma unroll
            for (int ks = 0; ks < 4; ++ks)
#pragma unroll
                for (int nt = 0; nt < 4; ++nt)
                    P[nt] = __builtin_amdgcn_mfma_f32_16x16x32_f16(
                        aB[ks], hf[nt][ks], ks == 0 ? zero4 : P[nt], 0, 0, 0);
#pragma unroll
            for (int nt = 0; nt < 4; ++nt)
#pragma unroll
                for (int r = 0; r < 4; ++r) msg[nt][r] += gv[nt] * P[nt][r];
        }
    }

    // ---- bias: msg[i,e] += sum_j b2[i*64+j]*g[e,j]  (this wave's rows)
#pragma unroll
    for (int ks2 = 0; ks2 < 2; ++ks2) {
        half8 gf[4];
#pragma unroll
        for (int nt = 0; nt < 4; ++nt) {
            const float* gp = &xsh[(nt * 16 + (lane & 15)) * 68 + ks2 * 32 + ((lane >> 4) & 3) * 8];
            float4 lo = *(const float4*)gp;
            float4 hi = *(const float4*)(gp + 4);
            half8 g8;
            g8[0] = (_Float16)lo.x; g8[1] = (_Float16)lo.y;
            g8[2] = (_Float16)lo.z; g8[3] = (_Float16)lo.w;
            g8[4] = (_Float16)hi.x; g8[5] = (_Float16)hi.y;
            g8[6] = (_Float16)hi.z; g8[7] = (_Float16)hi.w;
            gf[nt] = g8;
        }
        half8 bf8 = ((const half8*)b2pk)[ks2 * 256 + mt * 64 + lane];
#pragma unroll
        for (int nt = 0; nt < 4; ++nt)
            msg[nt] = __builtin_amdgcn_mfma_f32_16x16x32_f16(bf8, gf[nt], msg[nt], 0, 0, 0);
    }

    // ---- each wave writes its exclusive 16 rows of msgred
#pragma unroll
    for (int nt = 0; nt < 4; ++nt)
#pragma unroll
        for (int r = 0; r < 4; ++r) {
            int i = mt * 16 + ((lane >> 4) & 3) * 4 + r;
            int e = nt * 16 + (lane & 15);
            msgred[i * 67 + e] = msg[nt][r];
        }
    __syncthreads();

    // ---- scatter, coalesced: one edge row per atomic instr (lane = dim i)
#pragma unroll 1
    for (int ee = mt; ee < 64; ee += 4) {
        int d = dsts[ee];
        if (e0 + ee < N_EDGES && (unsigned)d < (unsigned)N_NODES)
            atomicAdd(agg + (size_t)d * NODE_DIM + lane, msgred[lane * 67 + ee]);
    }
}

// ---------------------------------------------------------------- phase 3
// GRUCell via MFMA (r15-proven).
__global__ __launch_bounds__(256) void gru_mfma_kernel(
    const float* __restrict__ agg,
    const float* __restrict__ x,
    const _Float16* __restrict__ gpk,
    const float* __restrict__ b_ih,
    const float* __restrict__ b_hh,
    float* __restrict__ out)
{
    const int t = threadIdx.x, wave = t >> 6, lane = t & 63;
    const int n0 = blockIdx.x * 64;

    int arow = n0 + wave * 16 + (lane & 15);
    if (arow >= N_NODES) arow = N_NODES - 1;
    const int kcol = ((lane >> 4) & 3) * 8;
    half8 aF[2], xF[2];   // [ks]
#pragma unroll
    for (int ks = 0; ks < 2; ++ks) {
        const float* ap = agg + (size_t)arow * 64 + ks * 32 + kcol;
        const float* xp = x   + (size_t)arow * 64 + ks * 32 + kcol;
        float4 a0 = *(const float4*)ap, a1 = *(const float4*)(ap + 4);
        float4 x0 = *(const float4*)xp, x1 = *(const float4*)(xp + 4);
        half8 af, xf;
        af[0] = (_Float16)a0.x; af[1] = (_Float16)a0.y; af[2] = (_Float16)a0.z; af[3] = (_Float16)a0.w;
        af[4] = (_Float16)a1.x; af[5] = (_Float16)a1.y; af[6] = (_Float16)a1.z; af[7] = (_Float16)a1.w;
        xf[0] = (_Float16)x0.x; xf[1] = (_Float16)x0.y; xf[2] = (_Float16)x0.z; xf[3] = (_Float16)x0.w;
        xf[4] = (_Float16)x1.x; xf[5] = (_Float16)x1.y; xf[6] = (_Float16)x1.z; xf[7] = (_Float16)x1.w;
        aF[ks] = af; xF[ks] = xf;
    }

    const half8* g8 = (const half8*)gpk;
    const f32x4 zero4 = {0.f, 0.f, 0.f, 0.f};
    f32x4 accI[12], accH[12];
#pragma unroll
    for (int nt = 0; nt < 12; ++nt) {
        half8 b0 = g8[((0 * 12 + nt) * 2 + 0) * 64 + lane];
        half8 b1f = g8[((0 * 12 + nt) * 2 + 1) * 64 + lane];
        f32x4 a = __builtin_amdgcn_mfma_f32_16x16x32_f16(aF[0], b0, zero4, 0, 0, 0);
        accI[nt] = __builtin_amdgcn_mfma_f32_16x16x32_f16(aF[1], b1f, a, 0, 0, 0);
        half8 c0 = g8[((1 * 12 + nt) * 2 + 0) * 64 + lane];
        half8 c1 = g8[((1 * 12 + nt) * 2 + 1) * 64 + lane];
        f32x4 h0 = __builtin_amdgcn_mfma_f32_16x16x32_f16(xF[0], c0, zero4, 0, 0, 0);
        accH[nt] = __builtin_amdgcn_mfma_f32_16x16x32_f16(xF[1], c1, h0, 0, 0, 0);
    }

    const int nodeBase = n0 + wave * 16 + ((lane >> 4) & 3) * 4;
    const int dlo = lane & 15;
#pragma unroll
    for (int q = 0; q < 4; ++q) {
        int d = q * 16 + dlo;
        float bi0 = b_ih[d], bi1 = b_ih[64 + d], bi2 = b_ih[128 + d];
        float bh0 = b_hh[d], bh1 = b_hh[64 + d], bh2 = b_hh[128 + d];
#pragma unroll
        for (int r = 0; r < 4; ++r) {
            int node = nodeBase + r;
            if (node < N_NODES) {
                float I0 = accI[q][r] + bi0, I1 = accI[q + 4][r] + bi1, I2 = accI[q + 8][r] + bi2;
                float H0 = accH[q][r] + bh0, H1 = accH[q + 4][r] + bh1, H2 = accH[q + 8][r] + bh2;
                float rg = 1.f / (1.f + expf(-(I0 + H0)));
                float z  = 1.f / (1.f + expf(-(I1 + H1)));
                float nn = tanhf(I2 + rg * H2);
                float xv = x[(size_t)node * 64 + d];
                out[(size_t)node * 64 + d] = (1.f - z) * nn + z * xv;
            }
        }
    }
}

// ---------------------------------------------------------------- launch
extern "C" void kernel_launch(void* const* d_in, const int* in_sizes, int n_in,
                              void* d_out, int out_size, void* d_ws, size_t ws_size,
                              hipStream_t stream)
{
    const float* x          = (const float*)d_in[0];
    const int*   edge_index = (const int*)  d_in[1];
    const float* edge_attr  = (const float*)d_in[2];
    const float* W1         = (const float*)d_in[3];
    const float* b1         = (const float*)d_in[4];
    const float* W2         = (const float*)d_in[5];
    const float* b2         = (const float*)d_in[6];
    const float* w_ih       = (const float*)d_in[7];
    const float* w_hh       = (const float*)d_in[8];
    const float* b_ih       = (const float*)d_in[9];
    const float* b_hh       = (const float*)d_in[10];
    float* out = (float*)d_out;

    // ws layout: identical offsets to round 5/9/15/16/19 (proven; 20,355,072 B).
    char* ws = (char*)d_ws;
    ws += (size_t)N_EDGES * HID * sizeof(_Float16);         // (unused hbuf slot, 12.8 MB)
    _Float16* Wpk  = (_Float16*)ws;                         // 1 MB
    ws += (size_t)65536 * 8 * sizeof(_Float16);
    _Float16* b2pk = (_Float16*)ws;                         // 8 KB
    ws += (size_t)512 * 8 * sizeof(_Float16);
    _Float16* gpk  = (_Float16*)ws;                         // 49,152 B within the two 48 KB slots
    ws += (size_t)64 * 192 * sizeof(float);                 // 48 KB
    ws += (size_t)64 * 192 * sizeof(float);                 // 48 KB
    float* agg = (float*)ws;                                // 6.4 MB (same offset)

    prep_kernel<<<dim3(G_MS + G_PK), dim3(256), 0, stream>>>(
        W2, b2, w_ih, w_hh, Wpk, b2pk, gpk, agg);

    edge_msg_mfma_kernel<<<dim3((N_EDGES + 63) / 64), dim3(256), 0, stream>>>(
        edge_attr, W1, b1, x, edge_index, Wpk, b2pk, agg);

    gru_mfma_kernel<<<dim3((N_NODES + 63) / 64), dim3(256), 0, stream>>>(
        agg, x, gpk, b_ih, b_hh, out);
}

// Round 23
// 92.630 us; speedup vs baseline: 1.4494x; 1.0178x over previous
//
#include <hip/hip_runtime.h>
#include <math.h>

// EdgeConditionedConv on MI355X — round 22: r21 + T5 s_setprio around the
// j-loop MFMA clusters. r19/r21's j-loop is barrier-free -> waves drift to
// different phases (the attn-like regime where setprio measured +4-7%);
// zero-risk scheduling hint on the proven body. Everything else r21-exact.

constexpr int N_NODES  = 25000;
constexpr int N_EDGES  = 50000;
constexpr int NODE_DIM = 64;
constexpr int EDGE_DIM = 16;
constexpr int HID      = 128;
constexpr int FS       = 65;           // hshf fragment stride (half8 units)

typedef __attribute__((ext_vector_type(8))) _Float16 half8;
typedef __attribute__((ext_vector_type(4))) float    f32x4;

constexpr int G_MS  = 128;             // agg-zero blocks
constexpr int G_PK  = 270;             // prepack blocks (270*256 = 69120 items)

// ---------------------------------------------------------------- prep
__global__ __launch_bounds__(256) void prep_kernel(
    const float* __restrict__ W2, const float* __restrict__ b2,
    const float* __restrict__ w_ih, const float* __restrict__ w_hh,
    _Float16* __restrict__ Wpk, _Float16* __restrict__ b2pk,
    _Float16* __restrict__ gpk, float* __restrict__ agg)
{
    int b = blockIdx.x;
    if (b < G_MS) {
        float4* a4 = (float4*)agg;
        const float4 z = make_float4(0.f, 0.f, 0.f, 0.f);
        for (int i = b * 256 + threadIdx.x; i < N_NODES * NODE_DIM / 4; i += G_MS * 256)
            a4[i] = z;
        return;
    }
    int c = (b - G_MS) * 256 + threadIdx.x;
    if (c < 65536) {
        int lane = c & 63, mt = (c >> 6) & 3, ks = (c >> 8) & 3, j = c >> 10;
        int i   = mt * 16 + (lane & 15);
        int col = ks * 32 + ((lane >> 4) & 3) * 8;
        const float* src = W2 + (size_t)(i * 64 + j) * HID + col;
        half8 o;
#pragma unroll
        for (int q = 0; q < 8; ++q) o[q] = (_Float16)src[q];
        ((half8*)Wpk)[c] = o;
    } else if (c < 65536 + 512) {
        int c2 = c - 65536;
        int lane = c2 & 63, mt = (c2 >> 6) & 3, ks2 = (c2 >> 8) & 1;
        int i = mt * 16 + (lane & 15);
        int j = ks2 * 32 + ((lane >> 4) & 3) * 8;
        const float* src = b2 + i * 64 + j;
        half8 o;
#pragma unroll
        for (int q = 0; q < 8; ++q) o[q] = (_Float16)src[q];
        ((half8*)b2pk)[c2] = o;
    } else if (c < 65536 + 512 + 3072) {
        // GRU weight fragments: chunk c3 = ((mat*12+nt)*2+ks)*64 + lane
        int c3 = c - (65536 + 512);
        int lane = c3 & 63, ks = (c3 >> 6) & 1;
        int t2 = c3 >> 7;             // mat*12 + nt, in [0,24)
        int nt = t2 % 12, mat = t2 / 12;
        int g = nt * 16 + (lane & 15);
        int k = ks * 32 + ((lane >> 4) & 3) * 8;
        const float* src = (mat == 0 ? w_ih : w_hh) + (size_t)g * 64 + k;
        half8 o;
#pragma unroll
        for (int q = 0; q < 8; ++q) o[q] = (_Float16)src[q];
        ((half8*)gpk)[c3] = o;
    }
}

// ---------------------------------------------------------------- phase 2
// r9-proven j-loop + in-block mlp1 (lane=edge, wave=k-range, broadcast W1).
// T5: setprio(1) around each j's MFMA cluster (waves are barrier-free here).
__global__ __launch_bounds__(256, 3) void edge_msg_mfma_kernel(
    const float*    __restrict__ edge_attr,
    const float*    __restrict__ W1,
    const float*    __restrict__ b1,
    const float*    __restrict__ x,
    const int*      __restrict__ edge_index,   // [2][E] int32
    const _Float16* __restrict__ Wpk,
    const _Float16* __restrict__ b2pk,
    float* __restrict__ agg)                   // [N][64], pre-zeroed
{
    __shared__ float xsh[64 * 68];      // gathered x[src], pitch 68 (17408 B)
    __shared__ float msgred[64 * 67];   // [i][e], pitch 67 (17152 B)
    __shared__ float W1s[128 * 16];     // 8192 B
    __shared__ float b1s[128];
    __shared__ int   dsts[64];
    half8* hshf = (half8*)msgred;       // alias: 16 fragments x FS=65 half8 (16640 B)

    const int e0   = blockIdx.x * 64;
    const int t    = threadIdx.x;
    const int mt   = t >> 6;            // wave id
    const int lane = t & 63;

    // ---- gather x[src[e]] rows into xsh (zero-fill invalid) + dsts
    {
        int le = t >> 2, sub = t & 3;
        int e = e0 + le;
        int s = -1;
        if (e < N_EDGES) {
            if (sub == 0) dsts[le] = edge_index[N_EDGES + e];
            s = edge_index[e];
        } else if (sub == 0) {
            dsts[le] = -1;
        }
#pragma unroll
        for (int q = 0; q < 4; ++q) {
            float4 v = make_float4(0.f, 0.f, 0.f, 0.f);
            if ((unsigned)s < (unsigned)N_NODES)
                v = ((const float4*)x)[(size_t)s * 16 + sub * 4 + q];
            *(float4*)&xsh[le * 68 + sub * 16 + q * 4] = v;
        }
    }

    // ---- stage W1/b1
#pragma unroll
    for (int r = 0; r < 8; ++r) W1s[t + r * 256] = W1[t + r * 256];
    if (t < 128) b1s[t] = b1[t];
    __syncthreads();

    // ---- in-block mlp1, wave-uniform k: wave ks computes k in
    // [ks*32, ks*32+32) for ALL 64 edges (lane = edge). W1s/b1s reads are
    // same-address broadcasts (conflict-free).
    // h[lane][k] -> hshf[((lane>>4)*4 + ks)*FS + kc*16 + (lane&15)].
    {
        const int ks = mt;              // this wave's k-range
        int e = e0 + lane;
        float ea[16];
        if (e < N_EDGES) {
            const float4* ea4 = (const float4*)(edge_attr + (size_t)e * EDGE_DIM);
#pragma unroll
            for (int q = 0; q < 4; ++q) {
                float4 v = ea4[q];
                ea[q * 4] = v.x; ea[q * 4 + 1] = v.y; ea[q * 4 + 2] = v.z; ea[q * 4 + 3] = v.w;
            }
        } else {
#pragma unroll
            for (int d = 0; d < 16; ++d) ea[d] = 0.f;
        }
        const int fbase = ((lane >> 4) * 4 + ks) * FS + (lane & 15);
#pragma unroll
        for (int kc = 0; kc < 4; ++kc) {      // 4 chunks of 8 k-values
            half8 hh;
#pragma unroll
            for (int kk = 0; kk < 8; ++kk) {
                int k = ks * 32 + kc * 8 + kk;      // wave-uniform
                float acc = b1s[k];
                const float* w = &W1s[k * 16];      // broadcast reads
#pragma unroll
                for (int d = 0; d < EDGE_DIM; ++d) acc += ea[d] * w[d];
                float g = 0.5f * acc * (1.0f + erff(acc * 0.70710678118654752f));
                hh[kk] = (_Float16)g;
            }
            hshf[fbase + kc * 16] = hh;
        }
    }
    __syncthreads();

    // ---- per-wave resident h fragments: lane-contiguous, conflict-free
    half8 hf[4][4];   // [nt][ks]
#pragma unroll
    for (int nt = 0; nt < 4; ++nt)
#pragma unroll
        for (int ks = 0; ks < 4; ++ks)
            hf[nt][ks] = hshf[(nt * 4 + ks) * FS + lane];
    __syncthreads();   // hshf dead after this point (msgred may overwrite)

    const f32x4 zero4 = {0.f, 0.f, 0.f, 0.f};
    f32x4 msg[4];
#pragma unroll
    for (int nt = 0; nt < 4; ++nt) msg[nt] = zero4;

    const half8* wpk8 = (const half8*)Wpk;
    const int mbase = mt * 64 + lane;

    half8 aA[4], aB[4];
#pragma unroll
    for (int ks = 0; ks < 4; ++ks) aA[ks] = wpk8[(size_t)mbase + ks * 256];  // j=0

#pragma unroll 1
    for (int j = 0; j < 64; j += 2) {
        {   // prefetch j+1
            size_t nb = (size_t)(j + 1) * 1024 + mbase;
#pragma unroll
            for (int ks = 0; ks < 4; ++ks) aB[ks] = wpk8[nb + ks * 256];
        }
        {   // compute j
            float gv[4];
#pragma unroll
            for (int nt = 0; nt < 4; ++nt) gv[nt] = xsh[(nt * 16 + (lane & 15)) * 68 + j];
            f32x4 P[4];
            __builtin_amdgcn_s_setprio(1);
#pragma unroll
            for (int ks = 0; ks < 4; ++ks)
#pragma unroll
                for (int nt = 0; nt < 4; ++nt)
                    P[nt] = __builtin_amdgcn_mfma_f32_16x16x32_f16(
                        aA[ks], hf[nt][ks], ks == 0 ? zero4 : P[nt], 0, 0, 0);
            __builtin_amdgcn_s_setprio(0);
#pragma unroll
            for (int nt = 0; nt < 4; ++nt)
#pragma unroll
                for (int r = 0; r < 4; ++r) msg[nt][r] += gv[nt] * P[nt][r];
        }
        if (j + 2 < 64) {   // prefetch j+2
            size_t nb = (size_t)(j + 2) * 1024 + mbase;
#pragma unroll
            for (int ks = 0; ks < 4; ++ks) aA[ks] = wpk8[nb + ks * 256];
        }
        {   // compute j+1
            float gv[4];
#pragma unroll
            for (int nt = 0; nt < 4; ++nt) gv[nt] = xsh[(nt * 16 + (lane & 15)) * 68 + j + 1];
            f32x4 P[4];
            __builtin_amdgcn_s_setprio(1);
#pragma unroll
            for (int ks = 0; ks < 4; ++ks)
#pragma unroll
                for (int nt = 0; nt < 4; ++nt)
                    P[nt] = __builtin_amdgcn_mfma_f32_16x16x32_f16(
                        aB[ks], hf[nt][ks], ks == 0 ? zero4 : P[nt], 0, 0, 0);
            __builtin_amdgcn_s_setprio(0);
#pragma unroll
            for (int nt = 0; nt < 4; ++nt)
#pragma unroll
                for (int r = 0; r < 4; ++r) msg[nt][r] += gv[nt] * P[nt][r];
        }
    }

    // ---- bias: msg[i,e] += sum_j b2[i*64+j]*g[e,j]  (this wave's rows)
#pragma unroll
    for (int ks2 = 0; ks2 < 2; ++ks2) {
        half8 gf[4];
#pragma unroll
        for (int nt = 0; nt < 4; ++nt) {
            const float* gp = &xsh[(nt * 16 + (lane & 15)) * 68 + ks2 * 32 + ((lane >> 4) & 3) * 8];
            float4 lo = *(const float4*)gp;
            float4 hi = *(const float4*)(gp + 4);
            half8 g8;
            g8[0] = (_Float16)lo.x; g8[1] = (_Float16)lo.y;
            g8[2] = (_Float16)lo.z; g8[3] = (_Float16)lo.w;
            g8[4] = (_Float16)hi.x; g8[5] = (_Float16)hi.y;
            g8[6] = (_Float16)hi.z; g8[7] = (_Float16)hi.w;
            gf[nt] = g8;
        }
        half8 bf8 = ((const half8*)b2pk)[ks2 * 256 + mt * 64 + lane];
#pragma unroll
        for (int nt = 0; nt < 4; ++nt)
            msg[nt] = __builtin_amdgcn_mfma_f32_16x16x32_f16(bf8, gf[nt], msg[nt], 0, 0, 0);
    }

    // ---- each wave writes its exclusive 16 rows of msgred
#pragma unroll
    for (int nt = 0; nt < 4; ++nt)
#pragma unroll
        for (int r = 0; r < 4; ++r) {
            int i = mt * 16 + ((lane >> 4) & 3) * 4 + r;
            int e = nt * 16 + (lane & 15);
            msgred[i * 67 + e] = msg[nt][r];
        }
    __syncthreads();

    // ---- scatter, coalesced: one edge row per atomic instr (lane = dim i)
#pragma unroll 1
    for (int ee = mt; ee < 64; ee += 4) {
        int d = dsts[ee];
        if (e0 + ee < N_EDGES && (unsigned)d < (unsigned)N_NODES)
            atomicAdd(agg + (size_t)d * NODE_DIM + lane, msgred[lane * 67 + ee]);
    }
}

// ---------------------------------------------------------------- phase 3
// GRUCell via MFMA (r15-proven).
__global__ __launch_bounds__(256) void gru_mfma_kernel(
    const float* __restrict__ agg,
    const float* __restrict__ x,
    const _Float16* __restrict__ gpk,
    const float* __restrict__ b_ih,
    const float* __restrict__ b_hh,
    float* __restrict__ out)
{
    const int t = threadIdx.x, wave = t >> 6, lane = t & 63;
    const int n0 = blockIdx.x * 64;

    int arow = n0 + wave * 16 + (lane & 15);
    if (arow >= N_NODES) arow = N_NODES - 1;
    const int kcol = ((lane >> 4) & 3) * 8;
    half8 aF[2], xF[2];   // [ks]
#pragma unroll
    for (int ks = 0; ks < 2; ++ks) {
        const float* ap = agg + (size_t)arow * 64 + ks * 32 + kcol;
        const float* xp = x   + (size_t)arow * 64 + ks * 32 + kcol;
        float4 a0 = *(const float4*)ap, a1 = *(const float4*)(ap + 4);
        float4 x0 = *(const float4*)xp, x1 = *(const float4*)(xp + 4);
        half8 af, xf;
        af[0] = (_Float16)a0.x; af[1] = (_Float16)a0.y; af[2] = (_Float16)a0.z; af[3] = (_Float16)a0.w;
        af[4] = (_Float16)a1.x; af[5] = (_Float16)a1.y; af[6] = (_Float16)a1.z; af[7] = (_Float16)a1.w;
        xf[0] = (_Float16)x0.x; xf[1] = (_Float16)x0.y; xf[2] = (_Float16)x0.z; xf[3] = (_Float16)x0.w;
        xf[4] = (_Float16)x1.x; xf[5] = (_Float16)x1.y; xf[6] = (_Float16)x1.z; xf[7] = (_Float16)x1.w;
        aF[ks] = af; xF[ks] = xf;
    }

    const half8* g8 = (const half8*)gpk;
    const f32x4 zero4 = {0.f, 0.f, 0.f, 0.f};
    f32x4 accI[12], accH[12];
#pragma unroll
    for (int nt = 0; nt < 12; ++nt) {
        half8 b0 = g8[((0 * 12 + nt) * 2 + 0) * 64 + lane];
        half8 b1f = g8[((0 * 12 + nt) * 2 + 1) * 64 + lane];
        f32x4 a = __builtin_amdgcn_mfma_f32_16x16x32_f16(aF[0], b0, zero4, 0, 0, 0);
        accI[nt] = __builtin_amdgcn_mfma_f32_16x16x32_f16(aF[1], b1f, a, 0, 0, 0);
        half8 c0 = g8[((1 * 12 + nt) * 2 + 0) * 64 + lane];
        half8 c1 = g8[((1 * 12 + nt) * 2 + 1) * 64 + lane];
        f32x4 h0 = __builtin_amdgcn_mfma_f32_16x16x32_f16(xF[0], c0, zero4, 0, 0, 0);
        accH[nt] = __builtin_amdgcn_mfma_f32_16x16x32_f16(xF[1], c1, h0, 0, 0, 0);
    }

    const int nodeBase = n0 + wave * 16 + ((lane >> 4) & 3) * 4;
    const int dlo = lane & 15;
#pragma unroll
    for (int q = 0; q < 4; ++q) {
        int d = q * 16 + dlo;
        float bi0 = b_ih[d], bi1 = b_ih[64 + d], bi2 = b_ih[128 + d];
        float bh0 = b_hh[d], bh1 = b_hh[64 + d], bh2 = b_hh[128 + d];
#pragma unroll
        for (int r = 0; r < 4; ++r) {
            int node = nodeBase + r;
            if (node < N_NODES) {
                float I0 = accI[q][r] + bi0, I1 = accI[q + 4][r] + bi1, I2 = accI[q + 8][r] + bi2;
                float H0 = accH[q][r] + bh0, H1 = accH[q + 4][r] + bh1, H2 = accH[q + 8][r] + bh2;
                float rg = 1.f / (1.f + expf(-(I0 + H0)));
                float z  = 1.f / (1.f + expf(-(I1 + H1)));
                float nn = tanhf(I2 + rg * H2);
                float xv = x[(size_t)node * 64 + d];
                out[(size_t)node * 64 + d] = (1.f - z) * nn + z * xv;
            }
        }
    }
}

// ---------------------------------------------------------------- launch
extern "C" void kernel_launch(void* const* d_in, const int* in_sizes, int n_in,
                              void* d_out, int out_size, void* d_ws, size_t ws_size,
                              hipStream_t stream)
{
    const float* x          = (const float*)d_in[0];
    const int*   edge_index = (const int*)  d_in[1];
    const float* edge_attr  = (const float*)d_in[2];
    const float* W1         = (const float*)d_in[3];
    const float* b1         = (const float*)d_in[4];
    const float* W2         = (const float*)d_in[5];
    const float* b2         = (const float*)d_in[6];
    const float* w_ih       = (const float*)d_in[7];
    const float* w_hh       = (const float*)d_in[8];
    const float* b_ih       = (const float*)d_in[9];
    const float* b_hh       = (const float*)d_in[10];
    float* out = (float*)d_out;

    // ws layout: identical offsets to round 5/9/15/16/19/21 (proven; 20,355,072 B).
    char* ws = (char*)d_ws;
    ws += (size_t)N_EDGES * HID * sizeof(_Float16);         // (unused hbuf slot, 12.8 MB)
    _Float16* Wpk  = (_Float16*)ws;                         // 1 MB
    ws += (size_t)65536 * 8 * sizeof(_Float16);
    _Float16* b2pk = (_Float16*)ws;                         // 8 KB
    ws += (size_t)512 * 8 * sizeof(_Float16);
    _Float16* gpk  = (_Float16*)ws;                         // 49,152 B within the two 48 KB slots
    ws += (size_t)64 * 192 * sizeof(float);                 // 48 KB
    ws += (size_t)64 * 192 * sizeof(float);                 // 48 KB
    float* agg = (float*)ws;                                // 6.4 MB (same offset)

    prep_kernel<<<dim3(G_MS + G_PK), dim3(256), 0, stream>>>(
        W2, b2, w_ih, w_hh, Wpk, b2pk, gpk, agg);

    edge_msg_mfma_kernel<<<dim3((N_EDGES + 63) / 64), dim3(256), 0, stream>>>(
        edge_attr, W1, b1, x, edge_index, Wpk, b2pk, agg);

    gru_mfma_kernel<<<dim3((N_NODES + 63) / 64), dim3(256), 0, stream>>>(
        agg, x, gpk, b_ih, b_hh, out);
}